// Round 10
// baseline (577.444 us; speedup 1.0000x reference)
//
#include <hip/hip_runtime.h>
#include <hip/hip_bf16.h>
#include <hip/hip_fp8.h>

#define TT 64   // timesteps
#define LL 64   // layers
#define BB 128  // batch
#define HH 64   // hidden
#define NP 32   // layer pairs (2 layers per WG)
#define SL 8    // batch slices
#define RR 16   // rows per slice

typedef short v8s __attribute__((ext_vector_type(8)));   // 8 bf16 (MFMA A/B frag)
typedef float v4f __attribute__((ext_vector_type(4)));   // MFMA C/D frag

// ws layout (bytes):
//   prog  : int[SL][32p] + red[2] (loss,cnt) @ 0    (16 KB reserved)
//   hglob : ull[16slot][32p][SL][16b][16w]   @ 16K  (8 MB) tagged fp8 words
//           low 32 = 4 x fp8-e4m3 (u = 4w..4w+3), high 32 = tag t
//   htop  : float[TT][HH][BB]                @ +8MB (2 MB)
//
// 2 layers per WG, 8 independent 16-row batch-slice chains. Waves 0-3 =
// layer 2p (A), waves 4-7 = layer 2p+1 (B); both compute t in superbeat t
// (R8/R9 schedule, validated). One barrier per timestep. Cross-WG edge only
// pair->pair via tagged fp8 words (tag rides with data -> poll IS the load).
// Weights gathered per-wave in the prologue (no reorder kernel); prog needs
// no init (0xAA poison < any t-14 threshold; first real ack lands at t=0).

__device__ __forceinline__ float sigm(float z)   {
    return __builtin_amdgcn_rcpf(1.f + __expf(-z));
}
__device__ __forceinline__ float tanh_f(float z) {
    return fmaf(-2.f, __builtin_amdgcn_rcpf(1.f + __expf(2.f * z)), 1.f);
}
__device__ __forceinline__ unsigned long long gload64(const unsigned long long* p) {
    return __hip_atomic_load(p, __ATOMIC_RELAXED, __HIP_MEMORY_SCOPE_AGENT);
}
__device__ __forceinline__ void gstore64(unsigned long long* p, unsigned long long v) {
    __hip_atomic_store(p, v, __ATOMIC_RELAXED, __HIP_MEMORY_SCOPE_AGENT);
}
__device__ __forceinline__ int fload(const int* p) {
    return __hip_atomic_load(p, __ATOMIC_RELAXED, __HIP_MEMORY_SCOPE_AGENT);
}
__device__ __forceinline__ void fstore(int* p, int v) {
    __hip_atomic_store(p, v, __ATOMIC_RELAXED, __HIP_MEMORY_SCOPE_AGENT);
}
__device__ __forceinline__ unsigned short f2bf(float f) {
    unsigned u = __float_as_uint(f);
    return (unsigned short)((u + 0x8000u) >> 16);
}

__global__ __launch_bounds__(512, 2) void lstm_pipeline(
    const float* __restrict__ x,    // [B][T]
    const float* __restrict__ W0,   // [65][256]
    const float* __restrict__ b0,   // [256]
    const float* __restrict__ Wl,   // [63][128][256]
    const float* __restrict__ bl,   // [63][256]
    int* __restrict__ prog,                   // [SL][32p] (+ red at 300/301)
    unsigned long long* __restrict__ hglob,   // [16][32][SL][16][16]
    float* __restrict__ htop)
{
    const int p   = blockIdx.x >> 3;
    const int s   = blockIdx.x & 7;  // batch slice: rows s*16 .. s*16+15
    const int tid = threadIdx.x;
    const int wv  = tid >> 6;
    const int la  = wv >> 2;         // 0 = layer 2p (A), 1 = layer 2p+1 (B)
    const int w   = wv & 3;          // u-stripe: units w*16 .. w*16+15
    const int ln  = tid & 63;
    const int lr  = ln & 15;
    const int qd  = ln >> 4;
    const int l   = 2 * p + la;

    __shared__ unsigned short hA[2][RR * 72];  // layer-A h, double-buffered
    __shared__ unsigned short hB[2][RR * 72];  // layer-B h
    __shared__ float xbuf[RR * 65];            // p==0 input staging

    if (blockIdx.x == 0 && tid < 2) fstore(&prog[300 + tid], 0);  // loss acc + cnt

    for (int i = tid; i < RR * 72; i += 512) {
        hA[0][i] = 0; hA[1][i] = 0; hB[0][i] = 0; hB[1][i] = 0;
    }
    if (p == 0) {
        for (int i = tid; i < RR * 64; i += 512)
            xbuf[(i >> 6) * 65 + (i & 63)] =
                x[(size_t)(s * RR + (i >> 6)) * TT + (i & 63)];
    }

    // ---- B-frag gather (one-time; hidden behind fill for p>0) ----
    // bfr[ga*4+kf][j] = W[k = kf*32 + qd*8 + j][gcol = ga*64 + w*16 + lr]
    v8s bfr[16];
#pragma unroll
    for (int f = 0; f < 16; ++f) {
        const int ga = f >> 2, kf = f & 3;
        const int gc = ga * 64 + w * 16 + lr;
        v8s tmp;
#pragma unroll
        for (int j = 0; j < 8; ++j) {
            const int k = kf * 32 + qd * 8 + j;
            float v;
            if (l > 0)       v = Wl[((size_t)(l - 1) * 128 + k) * 256 + gc];
            else if (k == 0) v = W0[gc];
            else if (k < 64) v = 0.f;
            else             v = W0[(size_t)(k - 63) * 256 + gc];
            tmp[j] = (short)f2bf(v);
        }
        bfr[f] = tmp;
    }

    const float* bs = l ? (bl + (l - 1) * 256) : b0;
    float bias[4];
#pragma unroll
    for (int ga = 0; ga < 4; ++ga) bias[ga] = bs[ga * 64 + w * 16 + lr];

    float cst[4];                    // c-state: one unit x 4 batch rows
#pragma unroll
    for (int i = 0; i < 4; ++i) cst[i] = 0.f;

    __syncthreads();

    for (int t = 0; t < TT; ++t) {
        const int cur = t & 1;

        if (la == 0) {
            // ================= A phase: layer 2p, timestep t =================
            unsigned int belowW[4];
            if (p > 0) {
                const unsigned long long* rp =
                    hglob + ((((size_t)(t & 15) * NP + (p - 1)) * SL + s) * RR + lr) * 16;
                for (;;) {                       // 4 polls in flight
                    unsigned long long v0 = gload64(rp + qd * 2);
                    unsigned long long v1 = gload64(rp + qd * 2 + 1);
                    unsigned long long v2 = gload64(rp + 8 + qd * 2);
                    unsigned long long v3 = gload64(rp + 8 + qd * 2 + 1);
                    unsigned int ok =
                        (unsigned int)((unsigned int)(v0 >> 32) == (unsigned int)t) &
                        (unsigned int)((unsigned int)(v1 >> 32) == (unsigned int)t) &
                        (unsigned int)((unsigned int)(v2 >> 32) == (unsigned int)t) &
                        (unsigned int)((unsigned int)(v3 >> 32) == (unsigned int)t);
                    if (ok) {
                        belowW[0] = (unsigned int)v0; belowW[1] = (unsigned int)v1;
                        belowW[2] = (unsigned int)v2; belowW[3] = (unsigned int)v3;
                        break;
                    }
                }
                if (tid == 0) fstore(&prog[s * NP + p], t + 1);  // consumed ack
            }

            v4f acc[4];
#pragma unroll
            for (int i = 0; i < 4; ++i) acc[i] = (v4f){0.f, 0.f, 0.f, 0.f};

            const int row = lr * 72;
            v8s a2 = *(const v8s*)&hA[cur ^ 1][row + qd * 8];       // own h(t-1)
            v8s a3 = *(const v8s*)&hA[cur ^ 1][row + 32 + qd * 8];
            v8s a0, a1;
            if (p > 0) {                                            // below = fp8
#pragma unroll
                for (int wi = 0; wi < 2; ++wi)
#pragma unroll
                    for (int bi = 0; bi < 4; ++bi) {
                        __hip_fp8_e4m3 f8;
                        f8.__x = (belowW[wi] >> (8 * bi)) & 0xff;
                        a0[wi * 4 + bi] = (short)f2bf((float)f8);
                        f8.__x = (belowW[2 + wi] >> (8 * bi)) & 0xff;
                        a1[wi * 4 + bi] = (short)f2bf((float)f8);
                    }
            } else {                                                // below = x_t
                a0 = (v8s){0, 0, 0, 0, 0, 0, 0, 0};
                a1 = (v8s){0, 0, 0, 0, 0, 0, 0, 0};
                if (qd == 0) a0[0] = (short)f2bf(xbuf[lr * 65 + t]);
            }
#pragma unroll
            for (int ga = 0; ga < 4; ++ga) {
                v4f c = acc[ga];
                c = __builtin_amdgcn_mfma_f32_16x16x32_bf16(a2, bfr[ga * 4 + 2], c, 0, 0, 0);
                c = __builtin_amdgcn_mfma_f32_16x16x32_bf16(a3, bfr[ga * 4 + 3], c, 0, 0, 0);
                c = __builtin_amdgcn_mfma_f32_16x16x32_bf16(a0, bfr[ga * 4 + 0], c, 0, 0, 0);
                c = __builtin_amdgcn_mfma_f32_16x16x32_bf16(a1, bfr[ga * 4 + 1], c, 0, 0, 0);
                acc[ga] = c;
            }
#pragma unroll
            for (int r = 0; r < 4; ++r) {
                float zi = acc[0][r] + bias[0];
                float zj = acc[1][r] + bias[1];
                float zf = acc[2][r] + bias[2];
                float zo = acc[3][r] + bias[3];
                float c2 = cst[r] * sigm(zf) + sigm(zi) * tanh_f(zj);
                cst[r] = c2;
                float h2 = tanh_f(c2) * sigm(zo);
                hA[cur][(qd * 4 + r) * 72 + w * 16 + lr] = f2bf(h2);
            }
        }

        __syncthreads();   // hA[cur] (t) visible to B; B(t-1) LDS writes visible

        if (la == 1) {
            // ================= B phase: layer 2p+1, timestep t ===============
            int gate = 0;
            if (p < NP - 1 && t >= 15)
                gate = fload(&prog[s * NP + (p + 1)]);   // prefetch gate value

            v4f acc[4];
#pragma unroll
            for (int i = 0; i < 4; ++i) acc[i] = (v4f){0.f, 0.f, 0.f, 0.f};

            const int row = lr * 72;
            v8s a2 = *(const v8s*)&hB[cur ^ 1][row + qd * 8];       // own h(t-1)
            v8s a3 = *(const v8s*)&hB[cur ^ 1][row + 32 + qd * 8];
            v8s a0 = *(const v8s*)&hA[cur][row + qd * 8];           // below h(t)
            v8s a1 = *(const v8s*)&hA[cur][row + 32 + qd * 8];
#pragma unroll
            for (int ga = 0; ga < 4; ++ga) {
                v4f c = acc[ga];
                c = __builtin_amdgcn_mfma_f32_16x16x32_bf16(a2, bfr[ga * 4 + 2], c, 0, 0, 0);
                c = __builtin_amdgcn_mfma_f32_16x16x32_bf16(a3, bfr[ga * 4 + 3], c, 0, 0, 0);
                c = __builtin_amdgcn_mfma_f32_16x16x32_bf16(a0, bfr[ga * 4 + 0], c, 0, 0, 0);
                c = __builtin_amdgcn_mfma_f32_16x16x32_bf16(a1, bfr[ga * 4 + 1], c, 0, 0, 0);
                acc[ga] = c;
            }
            // slot-reuse gate must pass before the tagged stores
            if (p < NP - 1 && t >= 15 && gate < t - 14)
                while (fload(&prog[s * NP + (p + 1)]) < t - 14) {}

            unsigned long long* dst =
                hglob + ((((size_t)(t & 15) * NP + p) * SL + s) * RR) * 16;
#pragma unroll
            for (int r = 0; r < 4; ++r) {
                float zi = acc[0][r] + bias[0];
                float zj = acc[1][r] + bias[1];
                float zf = acc[2][r] + bias[2];
                float zo = acc[3][r] + bias[3];
                float c2 = cst[r] * sigm(zf) + sigm(zi) * tanh_f(zj);
                cst[r] = c2;
                float h2 = tanh_f(c2) * sigm(zo);
                const int b = qd * 4 + r;
                const int u = w * 16 + lr;
                hB[cur][b * 72 + u] = f2bf(h2);
                if (p < NP - 1) {
                    __hip_fp8_e4m3 f8(h2);
                    unsigned int pk = ((unsigned int)f8.__x) << (8 * (lr & 3));
                    pk |= __shfl_xor(pk, 1);
                    pk |= __shfl_xor(pk, 2);
                    if ((lr & 3) == 0)
                        gstore64(dst + (size_t)b * 16 + w * 4 + (lr >> 2),
                                 (unsigned long long)pk |
                                 ((unsigned long long)(unsigned int)t << 32));
                } else {
                    htop[((size_t)t * HH + u) * BB + s * RR + b] = h2;
                }
            }
        }
        // no second barrier: A(t+1) writes hA[cur^1], disjoint from B(t) reads
    }
}

__global__ __launch_bounds__(128, 1) void epilogue(
    const float* __restrict__ htop, const float* __restrict__ Wd,
    const float* __restrict__ bd, const float* __restrict__ labels,
    float* __restrict__ out, int* __restrict__ prog)
{
    int t = blockIdx.x, b = threadIdx.x;  // 64 blocks x 128 threads
    float s = 0.f;
#pragma unroll 4
    for (int h = 0; h < HH; ++h)
        s = fmaf(htop[(size_t)t * HH * BB + h * BB + b], Wd[t * HH + h], s);
    s += bd[t];
    s = fmaxf(s, 0.f);
    out[b * TT + t] = s;                  // pred [B][T][1]
    float d = labels[b * TT + t] - s;
    float e = d * d;
#pragma unroll
    for (int off = 32; off > 0; off >>= 1) e += __shfl_down(e, off, 64);
    __shared__ float ws2[2];
    if ((b & 63) == 0) ws2[b >> 6] = e;
    __syncthreads();
    if (b == 0) {
        float* loss = (float*)&prog[300];
        atomicAdd(loss, ws2[0] + ws2[1]);             // device-scope
        __builtin_amdgcn_s_waitcnt(0);
        int done = __hip_atomic_fetch_add(&prog[301], 1, __ATOMIC_ACQ_REL,
                                          __HIP_MEMORY_SCOPE_AGENT);
        if (done == 63) {
            float tot = __hip_atomic_load(loss, __ATOMIC_RELAXED,
                                          __HIP_MEMORY_SCOPE_AGENT);
            out[BB * TT] = tot * (1.f / (BB * TT));
        }
    }
}

extern "C" void kernel_launch(void* const* d_in, const int* in_sizes, int n_in,
                              void* d_out, int out_size, void* d_ws, size_t ws_size,
                              hipStream_t stream) {
    const float* x      = (const float*)d_in[0];
    const float* labels = (const float*)d_in[1];
    const float* W0     = (const float*)d_in[2];
    const float* b0     = (const float*)d_in[3];
    const float* Wl     = (const float*)d_in[4];
    const float* bl     = (const float*)d_in[5];
    const float* Wd     = (const float*)d_in[6];
    const float* bd     = (const float*)d_in[7];
    float* out = (float*)d_out;

    char* base = (char*)d_ws;
    int*                prog  = (int*)base;
    unsigned long long* hglob = (unsigned long long*)(base + 16384);
    float*              htop  = (float*)(base + 16384 + 8388608);

    lstm_pipeline<<<NP * SL, 512, 0, stream>>>(x, W0, b0, Wl, bl, prog, hglob, htop);
    epilogue<<<64, 128, 0, stream>>>(htop, Wd, bd, labels, out, prog);
}

// Round 11
// 510.434 us; speedup vs baseline: 1.1313x; 1.1313x over previous
//
#include <hip/hip_runtime.h>
#include <hip/hip_bf16.h>
#include <hip/hip_fp8.h>

#define TT 64   // timesteps
#define LL 64   // layers
#define BB 128  // batch
#define HH 64   // hidden
#define GG 4    // layers per WG (intra-WG staggered)
#define NG 16   // WGs per chain (LL/GG)
#define SL 8    // batch slices
#define RR 16   // rows per slice
#define SB (TT + GG - 1)   // 67 superbeats

typedef short v8s __attribute__((ext_vector_type(8)));   // 8 bf16 (MFMA A/B frag)
typedef float v4f __attribute__((ext_vector_type(4)));   // MFMA C/D frag

// ws layout (bytes):
//   prog  : int[SL][NG] + red[2] @ 300       @ 0    (16 KB reserved)
//   hglob : ull[16slot][NG][SL][RR b][16 w]  @ 16K  (4 MB) tagged fp8 words
//           low 32 = 4 x fp8-e4m3 (u = 4w..4w+3), high 32 = tag t
//   htop  : float[TT][HH][BB]                @ +4MB (2 MB)
//
// Intra-WG layer stagger: 8 waves = 4 layers x 2 n-halves; layer k computes
// timestep t = sb - k at superbeat sb. ONE barrier per superbeat; all
// layer-edges inside the WG go through LDS dbuf (parity sb&1). Only 15
// cross-WG edges (WG g's L3 -> WG g+1's L0) via tagged fp8 words (tag rides
// with data -> poll IS the load; no fences). prog = lazy consumption acks
// for slot anti-overwrite (16-slot window, skew ~4 beats -> rarely binds).

__device__ __forceinline__ float sigm(float z)   {
    return __builtin_amdgcn_rcpf(1.f + __expf(-z));
}
__device__ __forceinline__ float tanh_f(float z) {
    return fmaf(-2.f, __builtin_amdgcn_rcpf(1.f + __expf(2.f * z)), 1.f);
}
__device__ __forceinline__ unsigned long long gload64(const unsigned long long* p) {
    return __hip_atomic_load(p, __ATOMIC_RELAXED, __HIP_MEMORY_SCOPE_AGENT);
}
__device__ __forceinline__ void gstore64(unsigned long long* p, unsigned long long v) {
    __hip_atomic_store(p, v, __ATOMIC_RELAXED, __HIP_MEMORY_SCOPE_AGENT);
}
__device__ __forceinline__ int fload(const int* p) {
    return __hip_atomic_load(p, __ATOMIC_RELAXED, __HIP_MEMORY_SCOPE_AGENT);
}
__device__ __forceinline__ void fstore(int* p, int v) {
    __hip_atomic_store(p, v, __ATOMIC_RELAXED, __HIP_MEMORY_SCOPE_AGENT);
}
__device__ __forceinline__ unsigned short f2bf(float f) {
    unsigned u = __float_as_uint(f);
    return (unsigned short)((u + 0x8000u) >> 16);
}

__global__ __launch_bounds__(512, 2) void lstm_pipeline(
    const float* __restrict__ x,    // [B][T]
    const float* __restrict__ W0,   // [65][256]
    const float* __restrict__ b0,   // [256]
    const float* __restrict__ Wl,   // [63][128][256]
    const float* __restrict__ bl,   // [63][256]
    int* __restrict__ prog,
    unsigned long long* __restrict__ hglob,   // [16][NG][SL][RR][16]
    float* __restrict__ htop)
{
    const int g   = blockIdx.x >> 3;
    const int s   = blockIdx.x & 7;  // batch slice: rows s*16 .. +15
    const int tid = threadIdx.x;
    const int wv  = tid >> 6;
    const int k   = wv >> 1;         // layer within WG (0..3), stagger t = sb-k
    const int nh  = wv & 1;          // n-half: units nh*32 .. +31
    const int ln  = tid & 63;
    const int lr  = ln & 15;
    const int qd  = ln >> 4;
    const int l   = GG * g + k;      // global layer

    __shared__ unsigned short hL[GG][2][RR * 72];  // per-layer h dbuf (18 KB)
    __shared__ float xbuf[RR * 65];                // g==0 input staging

    if (blockIdx.x == 0 && tid < 2) fstore(&prog[300 + tid], 0);  // loss acc+cnt

    for (int i = tid; i < GG * 2 * RR * 72; i += 512)
        ((unsigned short*)hL)[i] = 0;
    if (g == 0) {
        for (int i = tid; i < RR * 64; i += 512)
            xbuf[(i >> 6) * 65 + (i & 63)] =
                x[(size_t)(s * RR + (i >> 6)) * TT + (i & 63)];
    }

    // ---- B-frag gather (one-time): f = tn*4+kf, tn = ut*4+ga ----
    // B[kk][gcol]: kk = kf*32 + qd*8 + j ; gcol = ga*64 + nh*32 + ut*16 + lr.
    // kk<64: below rows; kk>=64: own rows. l==0: kk==0 -> W0 x-row, 1..63 -> 0,
    // kk>=64 -> W0[kk-63].
    v8s bfr[32];
#pragma unroll
    for (int f = 0; f < 32; ++f) {
        const int kf = f & 3, tn = f >> 2;
        const int ga = tn & 3, ut = tn >> 2;
        const int gc = ga * 64 + nh * 32 + ut * 16 + lr;
        v8s tmp;
#pragma unroll
        for (int j = 0; j < 8; ++j) {
            const int kk = kf * 32 + qd * 8 + j;
            float v;
            if (l > 0)        v = Wl[((size_t)(l - 1) * 128 + kk) * 256 + gc];
            else if (kk == 0) v = W0[gc];
            else if (kk < 64) v = 0.f;
            else              v = W0[(size_t)(kk - 63) * 256 + gc];
            tmp[j] = (short)f2bf(v);
        }
        bfr[f] = tmp;
    }

    const float* bs = l ? (bl + (l - 1) * 256) : b0;
    float bias[8];                   // [ut][ga]
#pragma unroll
    for (int i = 0; i < 8; ++i) {
        const int ut = i >> 2, ga = i & 3;
        bias[i] = bs[ga * 64 + nh * 32 + ut * 16 + lr];
    }

    float cst[8];                    // c-state: [ut][r]
#pragma unroll
    for (int i = 0; i < 8; ++i) cst[i] = 0.f;

    __syncthreads();

    for (int sb = 0; sb < SB; ++sb) {
        const int t = sb - k;
        const bool active = (t >= 0) && (t < TT);
        const int rd = (sb - 1) & 1, wr = sb & 1;

        if (active) {
            const int row = lr * 72;
            // own h(t-1) from this layer's dbuf (written at sb-1)
            v8s a2 = *(const v8s*)&hL[k][rd][row + qd * 8];
            v8s a3 = *(const v8s*)&hL[k][rd][row + 32 + qd * 8];
            v8s a0, a1;
            if (k > 0) {             // below = layer k-1's h(t), written at sb-1
                a0 = *(const v8s*)&hL[k - 1][rd][row + qd * 8];
                a1 = *(const v8s*)&hL[k - 1][rd][row + 32 + qd * 8];
            } else if (g > 0) {      // below = WG g-1's L3 tagged fp8 words
                const unsigned long long* rp =
                    hglob + ((((size_t)(t & 15) * NG + (g - 1)) * SL + s) * RR + lr) * 16;
                unsigned int bw0, bw1, bw2, bw3;
                for (;;) {           // 4 polls in flight; success = 1 RTT
                    unsigned long long v0 = gload64(rp + qd * 2);
                    unsigned long long v1 = gload64(rp + qd * 2 + 1);
                    unsigned long long v2 = gload64(rp + 8 + qd * 2);
                    unsigned long long v3 = gload64(rp + 8 + qd * 2 + 1);
                    unsigned int ok =
                        (unsigned int)((unsigned int)(v0 >> 32) == (unsigned int)t) &
                        (unsigned int)((unsigned int)(v1 >> 32) == (unsigned int)t) &
                        (unsigned int)((unsigned int)(v2 >> 32) == (unsigned int)t) &
                        (unsigned int)((unsigned int)(v3 >> 32) == (unsigned int)t);
                    if (ok) {
                        bw0 = (unsigned int)v0; bw1 = (unsigned int)v1;
                        bw2 = (unsigned int)v2; bw3 = (unsigned int)v3;
                        break;
                    }
                }
                if (nh == 0 && ln == 0) fstore(&prog[s * NG + g], t + 1);  // ack
                unsigned int ws4[4] = {bw0, bw1, bw2, bw3};
#pragma unroll
                for (int wi = 0; wi < 2; ++wi)
#pragma unroll
                    for (int bi = 0; bi < 4; ++bi) {
                        __hip_fp8_e4m3 f8;
                        f8.__x = (ws4[wi] >> (8 * bi)) & 0xff;
                        a0[wi * 4 + bi] = (short)f2bf((float)f8);
                        f8.__x = (ws4[2 + wi] >> (8 * bi)) & 0xff;
                        a1[wi * 4 + bi] = (short)f2bf((float)f8);
                    }
            } else {                 // global layer 0: below = x_t
                a0 = (v8s){0, 0, 0, 0, 0, 0, 0, 0};
                a1 = (v8s){0, 0, 0, 0, 0, 0, 0, 0};
                if (qd == 0) a0[0] = (short)f2bf(xbuf[lr * 65 + t]);
            }

            v4f acc[8];
#pragma unroll
            for (int i = 0; i < 8; ++i) acc[i] = (v4f){0.f, 0.f, 0.f, 0.f};
#pragma unroll
            for (int tn = 0; tn < 8; ++tn) {
                v4f c = acc[tn];
                c = __builtin_amdgcn_mfma_f32_16x16x32_bf16(a2, bfr[tn * 4 + 2], c, 0, 0, 0);
                c = __builtin_amdgcn_mfma_f32_16x16x32_bf16(a3, bfr[tn * 4 + 3], c, 0, 0, 0);
                c = __builtin_amdgcn_mfma_f32_16x16x32_bf16(a0, bfr[tn * 4 + 0], c, 0, 0, 0);
                c = __builtin_amdgcn_mfma_f32_16x16x32_bf16(a1, bfr[tn * 4 + 1], c, 0, 0, 0);
                acc[tn] = c;
            }

            // slot-reuse gate before k==3 tagged stores (rarely binding)
            if (k == 3 && g < NG - 1 && t >= 14)
                while (fload(&prog[s * NG + (g + 1)]) < t - 14) {}

            unsigned long long* dst =
                hglob + ((((size_t)(t & 15) * NG + g) * SL + s) * RR) * 16;
#pragma unroll
            for (int ut = 0; ut < 2; ++ut) {
                const int u = nh * 32 + ut * 16 + lr;
#pragma unroll
                for (int r = 0; r < 4; ++r) {
                    float zi = acc[ut * 4 + 0][r] + bias[ut * 4 + 0];
                    float zj = acc[ut * 4 + 1][r] + bias[ut * 4 + 1];
                    float zf = acc[ut * 4 + 2][r] + bias[ut * 4 + 2];
                    float zo = acc[ut * 4 + 3][r] + bias[ut * 4 + 3];
                    float c2 = cst[ut * 4 + r] * sigm(zf) + sigm(zi) * tanh_f(zj);
                    cst[ut * 4 + r] = c2;
                    float h2 = tanh_f(c2) * sigm(zo);
                    const int b = qd * 4 + r;
                    hL[k][wr][b * 72 + u] = f2bf(h2);
                    if (k == 3) {
                        if (g < NG - 1) {
                            __hip_fp8_e4m3 f8(h2);
                            unsigned int pk = ((unsigned int)f8.__x) << (8 * (lr & 3));
                            pk |= __shfl_xor(pk, 1);
                            pk |= __shfl_xor(pk, 2);
                            if ((lr & 3) == 0)
                                gstore64(dst + (size_t)b * 16 + nh * 8 + ut * 4 + (lr >> 2),
                                         (unsigned long long)pk |
                                         ((unsigned long long)(unsigned int)t << 32));
                        } else {
                            htop[((size_t)t * HH + u) * BB + s * RR + b] = h2;
                        }
                    }
                }
            }
        }
        __syncthreads();   // dbuf[wr] visible; all reads of dbuf[rd] done
    }
}

__global__ __launch_bounds__(128, 1) void epilogue(
    const float* __restrict__ htop, const float* __restrict__ Wd,
    const float* __restrict__ bd, const float* __restrict__ labels,
    float* __restrict__ out, int* __restrict__ prog)
{
    int t = blockIdx.x, b = threadIdx.x;  // 64 blocks x 128 threads
    float s = 0.f;
#pragma unroll 4
    for (int h = 0; h < HH; ++h)
        s = fmaf(htop[(size_t)t * HH * BB + h * BB + b], Wd[t * HH + h], s);
    s += bd[t];
    s = fmaxf(s, 0.f);
    out[b * TT + t] = s;                  // pred [B][T][1]
    float d = labels[b * TT + t] - s;
    float e = d * d;
#pragma unroll
    for (int off = 32; off > 0; off >>= 1) e += __shfl_down(e, off, 64);
    __shared__ float ws2[2];
    if ((b & 63) == 0) ws2[b >> 6] = e;
    __syncthreads();
    if (b == 0) {
        float* loss = (float*)&prog[300];
        atomicAdd(loss, ws2[0] + ws2[1]);             // device-scope
        __builtin_amdgcn_s_waitcnt(0);
        int done = __hip_atomic_fetch_add(&prog[301], 1, __ATOMIC_ACQ_REL,
                                          __HIP_MEMORY_SCOPE_AGENT);
        if (done == 63) {
            float tot = __hip_atomic_load(loss, __ATOMIC_RELAXED,
                                          __HIP_MEMORY_SCOPE_AGENT);
            out[BB * TT] = tot * (1.f / (BB * TT));
        }
    }
}

extern "C" void kernel_launch(void* const* d_in, const int* in_sizes, int n_in,
                              void* d_out, int out_size, void* d_ws, size_t ws_size,
                              hipStream_t stream) {
    const float* x      = (const float*)d_in[0];
    const float* labels = (const float*)d_in[1];
    const float* W0     = (const float*)d_in[2];
    const float* b0     = (const float*)d_in[3];
    const float* Wl     = (const float*)d_in[4];
    const float* bl     = (const float*)d_in[5];
    const float* Wd     = (const float*)d_in[6];
    const float* bd     = (const float*)d_in[7];
    float* out = (float*)d_out;

    char* base = (char*)d_ws;
    int*                prog  = (int*)base;
    unsigned long long* hglob = (unsigned long long*)(base + 16384);
    float*              htop  = (float*)(base + 16384 + 4194304);

    lstm_pipeline<<<NG * SL, 512, 0, stream>>>(x, W0, b0, Wl, bl, prog, hglob, htop);
    epilogue<<<64, 128, 0, stream>>>(htop, Wd, bd, labels, out, prog);
}